// Round 3
// baseline (296.565 us; speedup 1.0000x reference)
//
#include <hip/hip_runtime.h>
#include <hip/hip_bf16.h>

typedef short v8s __attribute__((ext_vector_type(8)));
typedef float v4f __attribute__((ext_vector_type(4)));

#define LDK 72                    // padded LDS row stride (bf16 elems): 144 B, 16B-aligned rows
#define SCALE_LOG2E 0.18033688f   // (1/sqrt(64)) * log2(e)

struct MMRAParams {
    const float* q[4];
    const float* k[4];
    const float* v[4];
    const int*   rg[4];
    const int*   mask;
    float*       out;
};

__device__ __forceinline__ ushort f2bf(float f) {
    return __builtin_bit_cast(ushort, __float2bfloat16(f));
}

__global__ __launch_bounds__(256, 2)
void mmra_attn(MMRAParams P) {
    const int bid = blockIdx.x;       // 512 blocks; bid&7 = b*4+h for XCD L2 locality
    const int h = bid & 3;
    const int b = (bid >> 2) & 1;
    const int n = bid >> 3;           // region 0..63
    const int H0 = ((n >> 4) & 3) << 2;
    const int W0 = ((n >> 2) & 3) << 2;
    const int D0 = (n & 3) << 2;

    const int tid  = threadIdx.x;
    const int wave = tid >> 6;        // q-modality of this wave
    const int lane = tid & 63;
    const int l15  = lane & 15;
    const int quad = lane >> 4;

    __shared__ __align__(16) ushort Klds[64 * LDK];       // [token][c]  (bf16)
    __shared__ __align__(16) ushort Vlds[64 * LDK];       // [c][token]  (bf16, transposed)
    __shared__ __align__(16) ushort Plds[4][16 * LDK];    // per-wave P / Q staging tile

    // q/k/v elem idx (fp32) = (b*256 + h*64 + c)*4096 + y*256 + x*16 + z
    const int bh_base = (b * 256 + h * 64) * 4096;

    // ---------------- Q fragments (A-layout), fp32->bf16 at staging ----------------
    v8s qfrag[4][2];
    {
        const float* qsrc = P.q[wave];
        for (int rb = 0; rb < 4; ++rb) {        // rb = mt = p coordinate
            __syncthreads();                     // prior tile reads done before overwrite
            #pragma unroll
            for (int i = 0; i < 4; ++i) {       // i = q coordinate; c = lane
                int off = bh_base + lane * 4096 + (H0 + rb) * 256 + (W0 + i) * 16 + D0;
                float4 cv = *(const float4*)(qsrc + off);
                Plds[wave][(i * 4 + 0) * LDK + lane] = f2bf(cv.x);
                Plds[wave][(i * 4 + 1) * LDK + lane] = f2bf(cv.y);
                Plds[wave][(i * 4 + 2) * LDK + lane] = f2bf(cv.z);
                Plds[wave][(i * 4 + 3) * LDK + lane] = f2bf(cv.w);
            }
            __syncthreads();                     // writes visible before frag reads
            qfrag[rb][0] = *(const v8s*)&Plds[wave][l15 * LDK + quad * 8];
            qfrag[rb][1] = *(const v8s*)&Plds[wave][l15 * LDK + 32 + quad * 8];
        }
    }

    v4f  oacc[4][4];
    float mrow[4][4], lrow[4][4];
    #pragma unroll
    for (int mt = 0; mt < 4; ++mt) {
        #pragma unroll
        for (int r = 0; r < 4; ++r) { mrow[mt][r] = -1e30f; lrow[mt][r] = 0.f; }
        #pragma unroll
        for (int nt = 0; nt < 4; ++nt) oacc[mt][nt] = (v4f){0.f, 0.f, 0.f, 0.f};
    }

    const int rgbase = ((b * 4 + h) * 64 + n) * 4;

    for (int cj = 0; cj < 16; ++cj) {             // chunk = (modality, topk-slot)
        const int mod = cj >> 2;
        const int j   = cj & 3;
        const bool active = (P.mask[b * 4 + mod] != 0);   // block-uniform
        const float* ksrc = P.k[mod];
        const float* vsrc = P.v[mod];
        const int g  = P.rg[mod][rgbase + j] & 63;        // defensive clamp to [0,64)
        const int GH = ((g >> 4) & 3) << 2;
        const int GW = ((g >> 2) & 3) << 2;
        const int GD = (g & 3) << 2;

        if (!active) continue;                     // uniform skip == -inf mask

        __syncthreads();   // prior chunk's frag reads complete before restage

        // ---- cooperative staging: c = lane, pq = wave*4 + i ----
        #pragma unroll
        for (int i = 0; i < 4; ++i) {
            const int pq = wave * 4 + i;
            const int pp = pq >> 2, qq = pq & 3;
            int off = bh_base + lane * 4096 + (GH + pp) * 256 + (GW + qq) * 16 + GD;
            float4 kf = *(const float4*)(ksrc + off);
            float4 vf = *(const float4*)(vsrc + off);
            Klds[(pq * 4 + 0) * LDK + lane] = f2bf(kf.x);   // lanes span banks
            Klds[(pq * 4 + 1) * LDK + lane] = f2bf(kf.y);
            Klds[(pq * 4 + 2) * LDK + lane] = f2bf(kf.z);
            Klds[(pq * 4 + 3) * LDK + lane] = f2bf(kf.w);
            union { uint2 u; ushort s[4]; } vv;
            vv.s[0] = f2bf(vf.x); vv.s[1] = f2bf(vf.y);
            vv.s[2] = f2bf(vf.z); vv.s[3] = f2bf(vf.w);
            *(uint2*)&Vlds[lane * LDK + pq * 4] = vv.u;     // transposed, packed 8B
        }
        __syncthreads();

        // ---- per-wave fragments ----
        v8s kfrag[4][2], vfrag[4][2];
        #pragma unroll
        for (int t = 0; t < 4; ++t) {
            kfrag[t][0] = *(const v8s*)&Klds[(t * 16 + l15) * LDK + quad * 8];
            kfrag[t][1] = *(const v8s*)&Klds[(t * 16 + l15) * LDK + 32 + quad * 8];
            vfrag[t][0] = *(const v8s*)&Vlds[(t * 16 + l15) * LDK + quad * 8];
            vfrag[t][1] = *(const v8s*)&Vlds[(t * 16 + l15) * LDK + 32 + quad * 8];
        }

        #pragma unroll
        for (int mt = 0; mt < 4; ++mt) {
            // S = Q K^T (fp32), then to log2 domain
            float sv[4][4];
            #pragma unroll
            for (int nt = 0; nt < 4; ++nt) {
                v4f acc = (v4f){0.f, 0.f, 0.f, 0.f};
                acc = __builtin_amdgcn_mfma_f32_16x16x32_bf16(qfrag[mt][0], kfrag[nt][0], acc, 0, 0, 0);
                acc = __builtin_amdgcn_mfma_f32_16x16x32_bf16(qfrag[mt][1], kfrag[nt][1], acc, 0, 0, 0);
                #pragma unroll
                for (int r = 0; r < 4; ++r) sv[nt][r] = acc[r] * SCALE_LOG2E;
            }
            // row max across cols: in-lane over nt, then across the 16 lanes of this quad
            float rmax[4];
            #pragma unroll
            for (int r = 0; r < 4; ++r)
                rmax[r] = fmaxf(fmaxf(sv[0][r], sv[1][r]), fmaxf(sv[2][r], sv[3][r]));
            #pragma unroll
            for (int off = 1; off < 16; off <<= 1) {
                #pragma unroll
                for (int r = 0; r < 4; ++r)
                    rmax[r] = fmaxf(rmax[r], __shfl_xor(rmax[r], off));
            }
            float mnew[4], alpha[4];
            #pragma unroll
            for (int r = 0; r < 4; ++r) {
                mnew[r]  = fmaxf(mrow[mt][r], rmax[r]);
                alpha[r] = exp2f(mrow[mt][r] - mnew[r]);
                mrow[mt][r] = mnew[r];
            }
            // P = exp2(S - m): write C-layout tile to per-wave LDS, reload in A-layout
            __syncthreads();   // prior P-tile reads (or Q staging reads) complete
            float rsum[4] = {0.f, 0.f, 0.f, 0.f};
            #pragma unroll
            for (int nt = 0; nt < 4; ++nt) {
                #pragma unroll
                for (int r = 0; r < 4; ++r) {
                    float pv = exp2f(sv[nt][r] - mnew[r]);
                    rsum[r] += pv;
                    Plds[wave][(quad * 4 + r) * LDK + nt * 16 + l15] = f2bf(pv);
                }
            }
            #pragma unroll
            for (int off = 1; off < 16; off <<= 1) {
                #pragma unroll
                for (int r = 0; r < 4; ++r)
                    rsum[r] += __shfl_xor(rsum[r], off);
            }
            #pragma unroll
            for (int r = 0; r < 4; ++r)
                lrow[mt][r] = lrow[mt][r] * alpha[r] + rsum[r];
            #pragma unroll
            for (int nt = 0; nt < 4; ++nt) {
                #pragma unroll
                for (int r = 0; r < 4; ++r) oacc[mt][nt][r] *= alpha[r];
            }
            __syncthreads();   // P writes visible before A-layout reload
            v8s pf0 = *(const v8s*)&Plds[wave][l15 * LDK + quad * 8];
            v8s pf1 = *(const v8s*)&Plds[wave][l15 * LDK + 32 + quad * 8];
            #pragma unroll
            for (int nt = 0; nt < 4; ++nt) {
                oacc[mt][nt] = __builtin_amdgcn_mfma_f32_16x16x32_bf16(pf0, vfrag[nt][0], oacc[mt][nt], 0, 0, 0);
                oacc[mt][nt] = __builtin_amdgcn_mfma_f32_16x16x32_bf16(pf1, vfrag[nt][1], oacc[mt][nt], 0, 0, 0);
            }
        }
    }

    // ---------------- epilogue: O /= l, seq2grid, fp32 float4 stores (reg == z coord) ----------------
    const int obase = (wave * 2 + b) * 1048576 + h * 64 * 4096;
    #pragma unroll
    for (int mt = 0; mt < 4; ++mt) {
        float inv[4];
        #pragma unroll
        for (int r = 0; r < 4; ++r) inv[r] = 1.0f / lrow[mt][r];
        #pragma unroll
        for (int nt = 0; nt < 4; ++nt) {
            float4 ov;
            ov.x = oacc[mt][nt][0] * inv[0];
            ov.y = oacc[mt][nt][1] * inv[1];
            ov.z = oacc[mt][nt][2] * inv[2];
            ov.w = oacc[mt][nt][3] * inv[3];
            int off = obase + (nt * 16 + l15) * 4096 + (H0 + mt) * 256 + (W0 + quad) * 16 + D0;
            *(float4*)(P.out + off) = ov;
        }
    }
}

extern "C" void kernel_launch(void* const* d_in, const int* in_sizes, int n_in,
                              void* d_out, int out_size, void* d_ws, size_t ws_size,
                              hipStream_t stream) {
    (void)in_sizes; (void)n_in; (void)out_size; (void)d_ws; (void)ws_size;
    MMRAParams P;
    P.mask = (const int*)d_in[0];
    for (int i = 0; i < 4; ++i) {
        P.q[i]  = (const float*)d_in[1 + i];
        P.k[i]  = (const float*)d_in[5 + i];
        P.v[i]  = (const float*)d_in[9 + i];
        P.rg[i] = (const int*)d_in[13 + i];
    }
    P.out = (float*)d_out;
    hipLaunchKernelGGL(mmra_attn, dim3(512), dim3(256), 0, stream, P);
}

// Round 6
// 289.041 us; speedup vs baseline: 1.0260x; 1.0260x over previous
//
#include <hip/hip_runtime.h>
#include <hip/hip_bf16.h>

typedef short v8s __attribute__((ext_vector_type(8)));
typedef float v4f __attribute__((ext_vector_type(4)));

#define LDK 72                    // padded LDS row stride (bf16 elems): 144 B, 16B-aligned rows
#define SCALE_LOG2E 0.18033688f   // (1/sqrt(64)) * log2(e), folded into Q at staging

struct MMRAParams {
    const float* q[4];
    const float* k[4];
    const float* v[4];
    const int*   rg[4];
    const int*   mask;
    float*       out;
};

__device__ __forceinline__ ushort f2bf(float f) {
    return __builtin_bit_cast(ushort, __float2bfloat16(f));
}
__device__ __forceinline__ unsigned int pk2bf(float a, float b) {
    return (unsigned int)f2bf(a) | ((unsigned int)f2bf(b) << 16);   // low = a, high = b
}

__global__ __launch_bounds__(256, 2)
void mmra_attn(MMRAParams P) {
    const int bid = blockIdx.x;       // 512 blocks; bid&7 = b*4+h for XCD L2 locality
    const int h = bid & 3;
    const int b = (bid >> 2) & 1;
    const int n = bid >> 3;           // region 0..63
    const int H0 = ((n >> 4) & 3) << 2;
    const int W0 = ((n >> 2) & 3) << 2;
    const int D0 = (n & 3) << 2;

    const int tid  = threadIdx.x;
    const int wave = tid >> 6;        // q-modality of this wave
    const int lane = tid & 63;
    const int l15  = lane & 15;
    const int quad = lane >> 4;

    __shared__ __align__(16) ushort Klds[64 * LDK];       // [token][c]  (bf16)
    __shared__ __align__(16) ushort Vlds[64 * LDK];       // [c][token]  (bf16, transposed)
    __shared__ __align__(16) ushort Plds[4][16 * LDK];    // per-wave private P tile / Q staging

    const int bh_base = (b * 256 + h * 64) * 4096;        // fp32 elem idx base
    const int rgbase  = ((b * 4 + h) * 64 + n) * 4;

    auto kptr = [&](int m) { return (m == 0) ? P.k[0] : (m == 1) ? P.k[1] : (m == 2) ? P.k[2] : P.k[3]; };
    auto vptr = [&](int m) { return (m == 0) ? P.v[0] : (m == 1) ? P.v[1] : (m == 2) ? P.v[2] : P.v[3]; };
    auto rptr = [&](int m) { return (m == 0) ? P.rg[0] : (m == 1) ? P.rg[1] : (m == 2) ? P.rg[2] : P.rg[3]; };

    // ---------------- chunk prefetch registers ----------------
    float4 pkf[4], pvf[4];
    auto prefetch = [&](int cj) {
        const int mod = cj >> 2, j = cj & 3;
        const int g = rptr(mod)[rgbase + j] & 63;
        const int goff = (((g >> 4) & 3) << 10) + (((g >> 2) & 3) << 6) + ((g & 3) << 2);
        const float* ks = kptr(mod);
        const float* vs = vptr(mod);
        const int off0 = bh_base + lane * 4096 + goff;
        #pragma unroll
        for (int i = 0; i < 4; ++i) {
            const int pq = wave * 4 + i;
            const int off = off0 + (pq >> 2) * 256 + (pq & 3) * 16;
            pkf[i] = *(const float4*)(ks + off);
            pvf[i] = *(const float4*)(vs + off);
        }
    };

    prefetch(0);   // chunk-0 loads overlap Q staging below

    // ------- Q staging: per-wave PRIVATE Plds[wave] (16*LDK), one 16-row rb-tile at a time -------
    // Q is pre-scaled by SCALE_LOG2E so S comes out directly in log2 domain.
    // Wave-local LDS round-trip: DS ops are in-order within a wave; lgkmcnt(0) orders write->read.
    v8s qfrag[4][2];
    {
        ushort* qbuf = &Plds[wave][0];
        const float* qsrc = (wave == 0) ? P.q[0] : (wave == 1) ? P.q[1] : (wave == 2) ? P.q[2] : P.q[3];
        for (int rb = 0; rb < 4; ++rb) {          // rb = p (y) coordinate = mt
            #pragma unroll
            for (int i = 0; i < 4; ++i) {         // i = x coordinate; c = lane
                int off = bh_base + lane * 4096 + (H0 + rb) * 256 + (W0 + i) * 16 + D0;
                float4 cv = *(const float4*)(qsrc + off);
                qbuf[(i * 4 + 0) * LDK + lane] = f2bf(cv.x * SCALE_LOG2E);
                qbuf[(i * 4 + 1) * LDK + lane] = f2bf(cv.y * SCALE_LOG2E);
                qbuf[(i * 4 + 2) * LDK + lane] = f2bf(cv.z * SCALE_LOG2E);
                qbuf[(i * 4 + 3) * LDK + lane] = f2bf(cv.w * SCALE_LOG2E);
            }
            __asm__ volatile("s_waitcnt lgkmcnt(0)" ::: "memory");   // writes visible to own wave
            qfrag[rb][0] = *(const v8s*)&qbuf[l15 * LDK + quad * 8];
            qfrag[rb][1] = *(const v8s*)&qbuf[l15 * LDK + 32 + quad * 8];
            __asm__ volatile("s_waitcnt lgkmcnt(0)" ::: "memory");   // reads done before next rb overwrite
        }
    }

    v4f  oacc[4][4];
    float mrow[4], lrow[4];       // softmax state per mt, indexed by q = l15 (dup across quads)
    #pragma unroll
    for (int mt = 0; mt < 4; ++mt) {
        mrow[mt] = -1e30f; lrow[mt] = 0.f;
        #pragma unroll
        for (int nt = 0; nt < 4; ++nt) oacc[mt][nt] = (v4f){0.f, 0.f, 0.f, 0.f};
    }

    #pragma unroll 1
    for (int cj = 0; cj < 16; ++cj) {             // chunk = (modality, topk-slot)
        const int mod = cj >> 2;
        const bool act = (P.mask[b * 4 + mod] != 0);   // block-uniform
        if (act) {
            __syncthreads();   // prior chunk's frag reads complete before restage
            #pragma unroll
            for (int i = 0; i < 4; ++i) {
                const int pq = wave * 4 + i;
                Klds[(pq * 4 + 0) * LDK + lane] = f2bf(pkf[i].x);
                Klds[(pq * 4 + 1) * LDK + lane] = f2bf(pkf[i].y);
                Klds[(pq * 4 + 2) * LDK + lane] = f2bf(pkf[i].z);
                Klds[(pq * 4 + 3) * LDK + lane] = f2bf(pkf[i].w);
                uint2 vv;
                vv.x = pk2bf(pvf[i].x, pvf[i].y);
                vv.y = pk2bf(pvf[i].z, pvf[i].w);
                *(uint2*)&Vlds[lane * LDK + pq * 4] = vv;   // transposed, packed 8B
            }
        }
        if (cj < 15) prefetch(cj + 1);     // overlaps the compute phase below
        if (!act) continue;                // uniform skip == -inf mask
        __syncthreads();

        // ---- per-wave K/V fragments ----
        v8s kfrag[4][2], vfrag[4][2];
        #pragma unroll
        for (int t = 0; t < 4; ++t) {
            kfrag[t][0] = *(const v8s*)&Klds[(t * 16 + l15) * LDK + quad * 8];
            kfrag[t][1] = *(const v8s*)&Klds[(t * 16 + l15) * LDK + 32 + quad * 8];
            vfrag[t][0] = *(const v8s*)&Vlds[(t * 16 + l15) * LDK + quad * 8];
            vfrag[t][1] = *(const v8s*)&Vlds[(t * 16 + l15) * LDK + 32 + quad * 8];
        }

        #pragma unroll
        for (int mt = 0; mt < 4; ++mt) {
            // S^T tile: D[m=key][n=q]  (A=K, B=Q swap). sv[nt][r]: key = nt*16+quad*4+r, q = l15.
            float sv[4][4];
            #pragma unroll
            for (int nt = 0; nt < 4; ++nt) {
                v4f acc = (v4f){0.f, 0.f, 0.f, 0.f};
                acc = __builtin_amdgcn_mfma_f32_16x16x32_bf16(kfrag[nt][0], qfrag[mt][0], acc, 0, 0, 0);
                acc = __builtin_amdgcn_mfma_f32_16x16x32_bf16(kfrag[nt][1], qfrag[mt][1], acc, 0, 0, 0);
                #pragma unroll
                for (int r = 0; r < 4; ++r) sv[nt][r] = acc[r];
            }
            // column (=q) max: in-lane over 16 values, then across quads (xor 16, 32)
            float mx = sv[0][0];
            #pragma unroll
            for (int nt = 0; nt < 4; ++nt)
                #pragma unroll
                for (int r = 0; r < 4; ++r) mx = fmaxf(mx, sv[nt][r]);
            mx = fmaxf(mx, __shfl_xor(mx, 16));
            mx = fmaxf(mx, __shfl_xor(mx, 32));
            const float mnew  = fmaxf(mrow[mt], mx);
            const float alpha = exp2f(mrow[mt] - mnew);
            mrow[mt] = mnew;

            // P = exp2(S - m): packed b64 writes into per-wave tile (rows = q, cols = key)
            float rsum = 0.f;
            #pragma unroll
            for (int nt = 0; nt < 4; ++nt) {
                float p0 = exp2f(sv[nt][0] - mnew);
                float p1 = exp2f(sv[nt][1] - mnew);
                float p2 = exp2f(sv[nt][2] - mnew);
                float p3 = exp2f(sv[nt][3] - mnew);
                rsum += (p0 + p1) + (p2 + p3);
                uint2 pw;
                pw.x = pk2bf(p0, p1);
                pw.y = pk2bf(p2, p3);
                *(uint2*)&Plds[wave][l15 * LDK + nt * 16 + quad * 4] = pw;
            }
            rsum += __shfl_xor(rsum, 16);
            rsum += __shfl_xor(rsum, 32);
            lrow[mt] = lrow[mt] * alpha + rsum;

            // transpose alpha from q=l15 indexing to O-row (q=quad*4+r) indexing
            float alpha_row[4];
            #pragma unroll
            for (int r = 0; r < 4; ++r)
                alpha_row[r] = __shfl(alpha, (quad << 4) | (quad * 4 + r));
            #pragma unroll
            for (int nt = 0; nt < 4; ++nt)
                #pragma unroll
                for (int r = 0; r < 4; ++r) oacc[mt][nt][r] *= alpha_row[r];

            __asm__ volatile("s_waitcnt lgkmcnt(0)" ::: "memory");   // wave-local P round-trip
            v8s pf0 = *(const v8s*)&Plds[wave][l15 * LDK + quad * 8];
            v8s pf1 = *(const v8s*)&Plds[wave][l15 * LDK + 32 + quad * 8];
            #pragma unroll
            for (int nt = 0; nt < 4; ++nt) {
                oacc[mt][nt] = __builtin_amdgcn_mfma_f32_16x16x32_bf16(pf0, vfrag[nt][0], oacc[mt][nt], 0, 0, 0);
                oacc[mt][nt] = __builtin_amdgcn_mfma_f32_16x16x32_bf16(pf1, vfrag[nt][1], oacc[mt][nt], 0, 0, 0);
            }
            __asm__ volatile("s_waitcnt lgkmcnt(0)" ::: "memory");   // P reads done before next mt writes
        }
    }

    // ---------------- epilogue: O /= l (quad-transposed), seq2grid, float4 stores ----------------
    const int obase = (wave * 2 + b) * 1048576 + h * 64 * 4096;
    #pragma unroll
    for (int mt = 0; mt < 4; ++mt) {
        const float invq = 1.0f / lrow[mt];
        float inv_row[4];
        #pragma unroll
        for (int r = 0; r < 4; ++r)
            inv_row[r] = __shfl(invq, (quad << 4) | (quad * 4 + r));
        #pragma unroll
        for (int nt = 0; nt < 4; ++nt) {
            float4 ov;
            ov.x = oacc[mt][nt][0] * inv_row[0];
            ov.y = oacc[mt][nt][1] * inv_row[1];
            ov.z = oacc[mt][nt][2] * inv_row[2];
            ov.w = oacc[mt][nt][3] * inv_row[3];
            int off = obase + (nt * 16 + l15) * 4096 + (H0 + mt) * 256 + (W0 + quad) * 16 + D0;
            *(float4*)(P.out + off) = ov;
        }
    }
}

extern "C" void kernel_launch(void* const* d_in, const int* in_sizes, int n_in,
                              void* d_out, int out_size, void* d_ws, size_t ws_size,
                              hipStream_t stream) {
    (void)in_sizes; (void)n_in; (void)out_size; (void)d_ws; (void)ws_size;
    MMRAParams P;
    P.mask = (const int*)d_in[0];
    for (int i = 0; i < 4; ++i) {
        P.q[i]  = (const float*)d_in[1 + i];
        P.k[i]  = (const float*)d_in[5 + i];
        P.v[i]  = (const float*)d_in[9 + i];
        P.rg[i] = (const int*)d_in[13 + i];
    }
    P.out = (float*)d_out;
    hipLaunchKernelGGL(mmra_attn, dim3(512), dim3(256), 0, stream, P);
}

// Round 7
// 256.950 us; speedup vs baseline: 1.1542x; 1.1249x over previous
//
#include <hip/hip_runtime.h>
#include <hip/hip_bf16.h>

typedef short v8s __attribute__((ext_vector_type(8)));
typedef float v4f __attribute__((ext_vector_type(4)));

#define LDK 72                    // padded LDS row stride (bf16 elems): 144 B, 16B-aligned rows
#define SCALE_LOG2E 0.18033688f   // (1/sqrt(64)) * log2(e), folded into Q at staging

struct MMRAParams {
    const float* q[4];
    const float* k[4];
    const float* v[4];
    const int*   rg[4];
    const int*   mask;
    float*       out;
};

// Fast RNE fp32->bf16 for KNOWN-FINITE values (3 VALU ops; no NaN handling).
__device__ __forceinline__ ushort f2bf(float f) {
    unsigned u = __builtin_bit_cast(unsigned, f);
    u += 0x7FFF + ((u >> 16) & 1);
    return (ushort)(u >> 16);
}
__device__ __forceinline__ unsigned int pk2bf(float a, float b) {
    return (unsigned int)f2bf(a) | ((unsigned int)f2bf(b) << 16);   // low = a, high = b
}

__global__ __launch_bounds__(256, 2)
void mmra_attn(MMRAParams P) {
    const int bid = blockIdx.x;       // 512 blocks; bid&7 = b*4+h for XCD L2 locality
    const int h = bid & 3;
    const int b = (bid >> 2) & 1;
    const int n = bid >> 3;           // region 0..63
    const int H0 = ((n >> 4) & 3) << 2;
    const int W0 = ((n >> 2) & 3) << 2;
    const int D0 = (n & 3) << 2;

    const int tid  = threadIdx.x;
    const int wave = tid >> 6;        // q-modality of this wave
    const int lane = tid & 63;
    const int l15  = lane & 15;
    const int quad = lane >> 4;

    __shared__ __align__(16) ushort Klds[64 * LDK];       // [token][c]  (bf16)
    __shared__ __align__(16) ushort Vlds[64 * LDK];       // [c][token]  (bf16, transposed)
    __shared__ __align__(16) ushort Plds[4][64 * LDK];    // per-wave private: 4 P tiles / Q staging

    const int bh_base = (b * 256 + h * 64) * 4096;        // fp32 elem idx base
    const int rgbase  = ((b * 4 + h) * 64 + n) * 4;

    const bool actm[4] = { P.mask[b * 4 + 0] != 0, P.mask[b * 4 + 1] != 0,
                           P.mask[b * 4 + 2] != 0, P.mask[b * 4 + 3] != 0 };

    auto kptr = [&](int m) { return (m == 0) ? P.k[0] : (m == 1) ? P.k[1] : (m == 2) ? P.k[2] : P.k[3]; };
    auto vptr = [&](int m) { return (m == 0) ? P.v[0] : (m == 1) ? P.v[1] : (m == 2) ? P.v[2] : P.v[3]; };
    auto rptr = [&](int m) { return (m == 0) ? P.rg[0] : (m == 1) ? P.rg[1] : (m == 2) ? P.rg[2] : P.rg[3]; };

    // ---------------- chunk prefetch registers ----------------
    float4 pkf[4], pvf[4];
    auto prefetch = [&](int cj) {
        const int mod = cj >> 2, j = cj & 3;
        const int g = rptr(mod)[rgbase + j] & 63;
        const int goff = (((g >> 4) & 3) << 10) + (((g >> 2) & 3) << 6) + ((g & 3) << 2);
        const float* ks = kptr(mod);
        const float* vs = vptr(mod);
        const int off0 = bh_base + lane * 4096 + goff;
        #pragma unroll
        for (int i = 0; i < 4; ++i) {
            const int pq = wave * 4 + i;
            const int off = off0 + (pq >> 2) * 256 + (pq & 3) * 16;
            pkf[i] = *(const float4*)(ks + off);
            pvf[i] = *(const float4*)(vs + off);
        }
    };

    prefetch(0);   // chunk-0 loads overlap Q staging below

    // ------- Q staging: per-wave PRIVATE Plds[wave] (64 rows), ONE drain -------
    // Q pre-scaled by SCALE_LOG2E so S comes out directly in log2 domain.
    v8s qfrag[4][2];
    {
        ushort* qbuf = &Plds[wave][0];
        const float* qsrc = (wave == 0) ? P.q[0] : (wave == 1) ? P.q[1] : (wave == 2) ? P.q[2] : P.q[3];
        #pragma unroll
        for (int rb = 0; rb < 4; ++rb) {          // rb = p (y) coordinate = mt
            #pragma unroll
            for (int i = 0; i < 4; ++i) {         // i = x coordinate; c = lane
                int off = bh_base + lane * 4096 + (H0 + rb) * 256 + (W0 + i) * 16 + D0;
                float4 cv = *(const float4*)(qsrc + off);
                qbuf[(rb * 16 + i * 4 + 0) * LDK + lane] = f2bf(cv.x * SCALE_LOG2E);
                qbuf[(rb * 16 + i * 4 + 1) * LDK + lane] = f2bf(cv.y * SCALE_LOG2E);
                qbuf[(rb * 16 + i * 4 + 2) * LDK + lane] = f2bf(cv.z * SCALE_LOG2E);
                qbuf[(rb * 16 + i * 4 + 3) * LDK + lane] = f2bf(cv.w * SCALE_LOG2E);
            }
        }
        __asm__ volatile("s_waitcnt lgkmcnt(0)" ::: "memory");   // wave-local write->read
        #pragma unroll
        for (int rb = 0; rb < 4; ++rb) {
            qfrag[rb][0] = *(const v8s*)&qbuf[(rb * 16 + l15) * LDK + quad * 8];
            qfrag[rb][1] = *(const v8s*)&qbuf[(rb * 16 + l15) * LDK + 32 + quad * 8];
        }
    }

    v4f  oacc[4][4];
    float mrow[4], lrow[4];       // softmax state per mt, indexed by q = l15 (dup across quads)
    #pragma unroll
    for (int mt = 0; mt < 4; ++mt) {
        mrow[mt] = -1e30f; lrow[mt] = 0.f;
        #pragma unroll
        for (int nt = 0; nt < 4; ++nt) oacc[mt][nt] = (v4f){0.f, 0.f, 0.f, 0.f};
    }

    #pragma unroll 1
    for (int cj = 0; cj < 16; ++cj) {             // chunk = (modality, topk-slot)
        const bool act = actm[cj >> 2];           // block-uniform
        if (act) {
            __syncthreads();   // prior chunk's K/V frag reads complete before restage
            #pragma unroll
            for (int i = 0; i < 4; ++i) {
                const int pq = wave * 4 + i;
                Klds[(pq * 4 + 0) * LDK + lane] = f2bf(pkf[i].x);
                Klds[(pq * 4 + 1) * LDK + lane] = f2bf(pkf[i].y);
                Klds[(pq * 4 + 2) * LDK + lane] = f2bf(pkf[i].z);
                Klds[(pq * 4 + 3) * LDK + lane] = f2bf(pkf[i].w);
                uint2 vv;
                vv.x = pk2bf(pvf[i].x, pvf[i].y);
                vv.y = pk2bf(pvf[i].z, pvf[i].w);
                *(uint2*)&Vlds[lane * LDK + pq * 4] = vv;   // transposed, packed 8B
            }
        }
        if (cj < 15) prefetch(cj + 1);     // overlaps phases A+B below
        if (!act) continue;                // uniform skip == -inf mask
        __syncthreads();

        // ================= PHASE A: QK^T + softmax + P-writes for ALL mt (no drains) ==========
        {
            v8s kfrag[4][2];
            #pragma unroll
            for (int t = 0; t < 4; ++t) {
                kfrag[t][0] = *(const v8s*)&Klds[(t * 16 + l15) * LDK + quad * 8];
                kfrag[t][1] = *(const v8s*)&Klds[(t * 16 + l15) * LDK + 32 + quad * 8];
            }
            #pragma unroll
            for (int mt = 0; mt < 4; ++mt) {
                // S^T tile: D[m=key][n=q]. sv[nt][r]: key = nt*16+quad*4+r, q = l15.
                float sv[4][4];
                #pragma unroll
                for (int nt = 0; nt < 4; ++nt) {
                    v4f acc = (v4f){0.f, 0.f, 0.f, 0.f};
                    acc = __builtin_amdgcn_mfma_f32_16x16x32_bf16(kfrag[nt][0], qfrag[mt][0], acc, 0, 0, 0);
                    acc = __builtin_amdgcn_mfma_f32_16x16x32_bf16(kfrag[nt][1], qfrag[mt][1], acc, 0, 0, 0);
                    #pragma unroll
                    for (int r = 0; r < 4; ++r) sv[nt][r] = acc[r];
                }
                // column (=q) max: in-lane over 16, then across quads (xor 16, 32)
                float mx = sv[0][0];
                #pragma unroll
                for (int nt = 0; nt < 4; ++nt)
                    #pragma unroll
                    for (int r = 0; r < 4; ++r) mx = fmaxf(mx, sv[nt][r]);
                mx = fmaxf(mx, __shfl_xor(mx, 16));
                mx = fmaxf(mx, __shfl_xor(mx, 32));
                const float mnew  = fmaxf(mrow[mt], mx);
                const float alpha = exp2f(mrow[mt] - mnew);
                mrow[mt] = mnew;

                // P = exp2(S - m): packed b64 writes to this wave's mt-th P tile (row=q, col=key)
                float rsum = 0.f;
                #pragma unroll
                for (int nt = 0; nt < 4; ++nt) {
                    float p0 = exp2f(sv[nt][0] - mnew);
                    float p1 = exp2f(sv[nt][1] - mnew);
                    float p2 = exp2f(sv[nt][2] - mnew);
                    float p3 = exp2f(sv[nt][3] - mnew);
                    rsum += (p0 + p1) + (p2 + p3);
                    uint2 pw;
                    pw.x = pk2bf(p0, p1);
                    pw.y = pk2bf(p2, p3);
                    *(uint2*)&Plds[wave][(mt * 16 + l15) * LDK + nt * 16 + quad * 4] = pw;
                }
                rsum += __shfl_xor(rsum, 16);
                rsum += __shfl_xor(rsum, 32);
                lrow[mt] = lrow[mt] * alpha + rsum;

                // rescale O: transpose alpha from q=l15 indexing to O-row (q=quad*4+r) indexing
                float alpha_row[4];
                #pragma unroll
                for (int r = 0; r < 4; ++r)
                    alpha_row[r] = __shfl(alpha, (quad << 4) | (quad * 4 + r));
                #pragma unroll
                for (int nt = 0; nt < 4; ++nt)
                    #pragma unroll
                    for (int r = 0; r < 4; ++r) oacc[mt][nt][r] *= alpha_row[r];
            }
        }

        // ================= PHASE B: one drain, then all PV MFMAs ==============================
        __asm__ volatile("s_waitcnt lgkmcnt(0)" ::: "memory");   // P writes visible to own wave
        {
            v8s vfrag[4][2];
            #pragma unroll
            for (int t = 0; t < 4; ++t) {
                vfrag[t][0] = *(const v8s*)&Vlds[(t * 16 + l15) * LDK + quad * 8];
                vfrag[t][1] = *(const v8s*)&Vlds[(t * 16 + l15) * LDK + 32 + quad * 8];
            }
            #pragma unroll
            for (int mt = 0; mt < 4; ++mt) {
                v8s pf0 = *(const v8s*)&Plds[wave][(mt * 16 + l15) * LDK + quad * 8];
                v8s pf1 = *(const v8s*)&Plds[wave][(mt * 16 + l15) * LDK + 32 + quad * 8];
                #pragma unroll
                for (int nt = 0; nt < 4; ++nt) {
                    oacc[mt][nt] = __builtin_amdgcn_mfma_f32_16x16x32_bf16(pf0, vfrag[nt][0], oacc[mt][nt], 0, 0, 0);
                    oacc[mt][nt] = __builtin_amdgcn_mfma_f32_16x16x32_bf16(pf1, vfrag[nt][1], oacc[mt][nt], 0, 0, 0);
                }
            }
        }
    }

    // ---------------- epilogue: O /= l (quad-transposed), seq2grid, float4 stores ----------------
    const int obase = (wave * 2 + b) * 1048576 + h * 64 * 4096;
    #pragma unroll
    for (int mt = 0; mt < 4; ++mt) {
        const float invq = 1.0f / lrow[mt];
        float inv_row[4];
        #pragma unroll
        for (int r = 0; r < 4; ++r)
            inv_row[r] = __shfl(invq, (quad << 4) | (quad * 4 + r));
        #pragma unroll
        for (int nt = 0; nt < 4; ++nt) {
            float4 ov;
            ov.x = oacc[mt][nt][0] * inv_row[0];
            ov.y = oacc[mt][nt][1] * inv_row[1];
            ov.z = oacc[mt][nt][2] * inv_row[2];
            ov.w = oacc[mt][nt][3] * inv_row[3];
            int off = obase + (nt * 16 + l15) * 4096 + (H0 + mt) * 256 + (W0 + quad) * 16 + D0;
            *(float4*)(P.out + off) = ov;
        }
    }
}

extern "C" void kernel_launch(void* const* d_in, const int* in_sizes, int n_in,
                              void* d_out, int out_size, void* d_ws, size_t ws_size,
                              hipStream_t stream) {
    (void)in_sizes; (void)n_in; (void)out_size; (void)d_ws; (void)ws_size;
    MMRAParams P;
    P.mask = (const int*)d_in[0];
    for (int i = 0; i < 4; ++i) {
        P.q[i]  = (const float*)d_in[1 + i];
        P.k[i]  = (const float*)d_in[5 + i];
        P.v[i]  = (const float*)d_in[9 + i];
        P.rg[i] = (const int*)d_in[13 + i];
    }
    P.out = (float*)d_out;
    hipLaunchKernelGGL(mmra_attn, dim3(512), dim3(256), 0, stream, P);
}